// Round 12
// baseline (884.284 us; speedup 1.0000x reference)
//
#include <hip/hip_runtime.h>
#include <cstddef>
#include <cstdint>

#define N_NODES 100000
#define N_EDGES 3200000
#define D 256
#define BSHIFT 9                                // 512 rows per bucket
#define NBUCK ((N_NODES + (1 << BSHIFT) - 1) >> BSHIFT)  // 196
#define EPB 4096                                // edges per pass-1 block
#define CAP 20480                               // staging slots per bucket

typedef __attribute__((ext_vector_type(8))) short bf16x8;
typedef __attribute__((ext_vector_type(4))) float f32x4;
typedef unsigned int u32;
typedef unsigned long long u64;

#define GLOAD16(gsrc, ldst)                                                      \
    __builtin_amdgcn_global_load_lds(                                            \
        (const __attribute__((address_space(1))) void*)(gsrc),                   \
        (__attribute__((address_space(3))) void*)(ldst), 16, 0, 0)

__device__ __forceinline__ ushort f2b(float f) {  // f32 -> bf16 RNE
    unsigned u = __float_as_uint(f);
    return (ushort)((u + 0x7fffu + ((u >> 16) & 1u)) >> 16);
}

// ---------------- bucket cursor init (fixed-capacity slots) ----------------
__global__ void cursorinit_kernel(int* __restrict__ bucket_cursor) {
    int b = blockIdx.x * 256 + threadIdx.x;
    if (b < NBUCK) bucket_cursor[b] = b * CAP;
}

// ---------------- binned scatter pass 1 ----------------
__global__ __launch_bounds__(256) void binpass1_kernel(const int* __restrict__ erow,
                                                       const int* __restrict__ ecol,
                                                       const float* __restrict__ evalv,
                                                       int* __restrict__ bucket_cursor,
                                                       int2* __restrict__ staging) {
    __shared__ int cnt[NBUCK];
    __shared__ int lstart[NBUCK];
    __shared__ int gbase[NBUCK];
    __shared__ int wtot[4];
    __shared__ int woff[4];
    __shared__ int2 lcv[EPB];            // 32 KB
    __shared__ unsigned char lbb[EPB];   // 4 KB
    const int tid = threadIdx.x;
    const size_t base = (size_t)blockIdx.x * EPB;
    for (int b = tid; b < NBUCK; b += 256) cnt[b] = 0;
    __syncthreads();
    int bb[16];
    int2 pcv[16];
    int loff[16];
#pragma unroll
    for (int i = 0; i < 16; ++i) {
        size_t e = base + (size_t)i * 256 + tid;
        if (e < N_EDGES) {
            int r = erow[e];
            int b = r >> BSHIFT;
            bb[i] = b;
            pcv[i] = make_int2(ecol[e] | ((r & ((1 << BSHIFT) - 1)) << 17),
                               __float_as_int(evalv[e]));
            loff[i] = atomicAdd(&cnt[b], 1);
        } else {
            bb[i] = -1;
        }
    }
    __syncthreads();
    {
        int b = tid;
        int v = (b < NBUCK) ? cnt[b] : 0;
        int lane = tid & 63, wv = tid >> 6;
        int inc = v;
#pragma unroll
        for (int off = 1; off < 64; off <<= 1) {
            int u = __shfl_up(inc, off, 64);
            if (lane >= off) inc += u;
        }
        if (lane == 63) wtot[wv] = inc;
        __syncthreads();
        if (tid == 0) {
            int run = 0;
#pragma unroll
            for (int w = 0; w < 4; ++w) { woff[w] = run; run += wtot[w]; }
        }
        __syncthreads();
        int exc = woff[wv] + inc - v;
        if (b < NBUCK) {
            lstart[b] = exc;
            if (v > 0) gbase[b] = atomicAdd(&bucket_cursor[b], v);
        }
    }
    __syncthreads();
#pragma unroll
    for (int i = 0; i < 16; ++i) {
        if (bb[i] >= 0) {
            int p = lstart[bb[i]] + loff[i];
            lcv[p] = pcv[i];
            lbb[p] = (unsigned char)bb[i];
        }
    }
    __syncthreads();
    const int total = lstart[NBUCK - 1] + cnt[NBUCK - 1];
    for (int p = tid; p < total; p += 256) {
        int b = lbb[p];
        int g = gbase[b] + (p - lstart[b]);
        staging[g] = lcv[p];
    }
}

// ---------------- binned scatter pass 2: count+scan in LDS, emit rowrange --------
__global__ __launch_bounds__(256) void binpass2_kernel(const int* __restrict__ bucket_cursor,
                                                       const int2* __restrict__ staging,
                                                       int2* __restrict__ cedge,
                                                       int2* __restrict__ rowrange) {
    __shared__ int cnt[1 << BSHIFT];
    __shared__ int scur[1 << BSHIFT];
    __shared__ int wtot[4];
    __shared__ int woff[4];
    const int b   = blockIdx.x;
    const int tid = threadIdx.x;
    const int base = b * CAP;
    const int hi   = bucket_cursor[b];
    for (int i = tid; i < (1 << BSHIFT); i += 256) cnt[i] = 0;
    __syncthreads();
    for (int k = base + tid; k < hi; k += 256)
        atomicAdd(&cnt[((u32)staging[k].x) >> 17], 1);
    __syncthreads();
    int v0 = cnt[2 * tid];
    int v1 = cnt[2 * tid + 1];
    int s = v0 + v1;
    int lane = tid & 63, wv = tid >> 6;
    int inc = s;
#pragma unroll
    for (int off = 1; off < 64; off <<= 1) {
        int u = __shfl_up(inc, off, 64);
        if (lane >= off) inc += u;
    }
    if (lane == 63) wtot[wv] = inc;
    __syncthreads();
    if (tid == 0) {
        int run = 0;
#pragma unroll
        for (int w = 0; w < 4; ++w) { woff[w] = run; run += wtot[w]; }
    }
    __syncthreads();
    int exc = woff[wv] + inc - s;
    int g0 = base + exc;
    scur[2 * tid]     = g0;
    scur[2 * tid + 1] = g0 + v0;
    const int r0 = b << BSHIFT;
    int r = r0 + 2 * tid;
    if (r < N_NODES)     rowrange[r]     = make_int2(g0, g0 + v0);
    if (r + 1 < N_NODES) rowrange[r + 1] = make_int2(g0 + v0, g0 + v0 + v1);
    __syncthreads();
    for (int k = base + tid; k < hi; k += 256) {
        int2 e = staging[k];
        int rloc = ((u32)e.x) >> 17;
        int pos = atomicAdd(&scur[rloc], 1);
        cedge[pos] = make_int2(e.x & 0x1FFFF, e.y);
    }
}

// ---------------- per-row edge sort by col (synchronized-sweep locality) ---------
// One wave per node; registers-only bitonic sort of <=128 packed u64 keys
// (col<<32 | valbits), 2 per lane. Rows with deg>128 (P~0) stay unsorted --
// sorting is a pure optimization, any within-row order is correct.
__global__ __launch_bounds__(256) void sortrow_kernel(const int2* __restrict__ rowrange,
                                                      int2* __restrict__ cedge) {
    const int node = (blockIdx.x << 2) + (threadIdx.x >> 6);
    const int lane = threadIdx.x & 63;
    int2 rr = rowrange[node];
    const int st = rr.x;
    const int deg = rr.y - rr.x;
    if (deg <= 1 || deg > 128) return;
    const u64 SENT = ~0ull;
    u64 v0 = SENT, v1 = SENT;
    if (lane < deg) {
        int2 e = cedge[st + lane];
        v0 = ((u64)(u32)e.x << 32) | (u32)e.y;
    }
    if (64 + lane < deg) {
        int2 e = cedge[st + 64 + lane];
        v1 = ((u64)(u32)e.x << 32) | (u32)e.y;
    }
#pragma unroll
    for (int k = 2; k <= 128; k <<= 1) {
#pragma unroll
        for (int j = 64; j >= 1; j >>= 1) {
            if (j > (k >> 1)) continue;
            if (j == 64) {
                // exchange idx=lane (v0) with idx=lane+64 (v1); k==128 -> ascending
                u64 lo = v0 < v1 ? v0 : v1;
                u64 hi = v0 < v1 ? v1 : v0;
                v0 = lo; v1 = hi;
            } else {
                bool up = (lane & j) == 0;
                bool asc0 = (lane & k) == 0;
                bool asc1 = ((lane + 64) & k) == 0;  // differs from asc0 only when k==64
                u64 p0 = __shfl_xor(v0, j, 64);
                u64 p1 = __shfl_xor(v1, j, 64);
                v0 = ((up == asc0) == (v0 < p0)) ? v0 : p0;
                v1 = ((up == asc1) == (v1 < p1)) ? v1 : p1;
            }
        }
    }
    if (lane < deg)
        cedge[st + lane] = make_int2((int)(v0 >> 32), (int)(u32)v0);
    if (64 + lane < deg)
        cedge[st + 64 + lane] = make_int2((int)(v1 >> 32), (int)(u32)v1);
}

// ---------------- f32 -> bf16 elementwise ----------------
__global__ __launch_bounds__(256) void cvt_kernel(const float* __restrict__ in,
                                                  ushort* __restrict__ out, int n4) {
    int i = blockIdx.x * 256 + threadIdx.x;
    if (i < n4) {
        float4 v = ((const float4*)in)[i];
        uint2 p;
        p.x = (unsigned)f2b(v.x) | ((unsigned)f2b(v.y) << 16);
        p.y = (unsigned)f2b(v.z) | ((unsigned)f2b(v.w) << 16);
        ((uint2*)out)[i] = p;
    }
}

// ---------------- both W [512][256] f32 -> Wt [256][512] bf16 (one launch) -------
__global__ __launch_bounds__(256) void wtrans_kernel(const float* __restrict__ W1,
                                                     const float* __restrict__ Wout,
                                                     ushort* __restrict__ W1t,
                                                     ushort* __restrict__ Woutt) {
    int t = blockIdx.x * 256 + threadIdx.x;       // 0..262143
    const float* W = (t < 131072) ? W1 : Wout;
    ushort* Wt     = (t < 131072) ? W1t : Woutt;
    int u = t & 131071;
    int j = u & 255;
    int k = u >> 8;
    Wt[(size_t)j * 512 + k] = f2b(W[(size_t)k * 256 + j]);
}

// ---------------- CSR SpMM (bf16 features): one wave per node (R6-proven) ---------
__global__ __launch_bounds__(256) void spmm_kernel(const int2* __restrict__ rowrange,
                                                   const int2* __restrict__ cedge,
                                                   const ushort* __restrict__ h,
                                                   ushort* __restrict__ outb) {
    const int node = (blockIdx.x << 2) + (threadIdx.x >> 6);
    const int lane = threadIdx.x & 63;
    const uint2* __restrict__ h2 = (const uint2*)h;
    int2 rr = rowrange[node];
    int k = rr.x;
    const int end = rr.y;
    float a0 = 0.f, a1 = 0.f, a2 = 0.f, a3 = 0.f;
#define EDGE_FMA(e, d)                                              \
    {                                                               \
        float v = __int_as_float((e).y);                            \
        a0 = fmaf(v, __uint_as_float((d).x << 16), a0);             \
        a1 = fmaf(v, __uint_as_float((d).x & 0xffff0000u), a1);     \
        a2 = fmaf(v, __uint_as_float((d).y << 16), a2);             \
        a3 = fmaf(v, __uint_as_float((d).y & 0xffff0000u), a3);     \
    }
    for (; k + 4 <= end; k += 4) {
        int2 e0 = cedge[k];
        int2 e1 = cedge[k + 1];
        int2 e2 = cedge[k + 2];
        int2 e3 = cedge[k + 3];
        uint2 d0 = h2[(size_t)e0.x * 64 + lane];
        uint2 d1 = h2[(size_t)e1.x * 64 + lane];
        uint2 d2 = h2[(size_t)e2.x * 64 + lane];
        uint2 d3 = h2[(size_t)e3.x * 64 + lane];
        EDGE_FMA(e0, d0)
        EDGE_FMA(e1, d1)
        EDGE_FMA(e2, d2)
        EDGE_FMA(e3, d3)
    }
    for (; k < end; ++k) {
        int2 e = cedge[k];
        uint2 d = h2[(size_t)e.x * 64 + lane];
        EDGE_FMA(e, d)
    }
#undef EDGE_FMA
    uint2 p;
    p.x = (unsigned)f2b(a0) | ((unsigned)f2b(a1) << 16);
    p.y = (unsigned)f2b(a2) | ((unsigned)f2b(a3) << 16);
    ((uint2*)outb)[(size_t)node * 64 + lane] = p;
}

// ---------------- MFMA concat-GEMM: BK=32, chunk-major LDS, 4 blocks/CU ----------
#define STAGE_TILE(bufbase, tt)                                                  \
    {                                                                            \
        const ushort* Ab_ = ((tt) < 8) ? A1 : A2;                                \
        const int k0_ = ((tt) & 7) * 32;                                         \
        GLOAD16(Ab_ + (size_t)rowA * 256 + k0_ + wid * 8,                        \
                lds + (bufbase) + wid * 1024);                                   \
        _Pragma("unroll")                                                        \
        for (int p = 0; p < 4; ++p)                                              \
            GLOAD16(wBsrc + (tt) * 32 + p * 8,                                   \
                    lds + (bufbase) + 4096 + (p * 4 + wid) * 1024);              \
    }

template <bool OUT_BF16>
__global__ __launch_bounds__(256, 4) void gemm_mfma_kernel(const ushort* __restrict__ A1,
                                                           const ushort* __restrict__ A2,
                                                           const ushort* __restrict__ Wt,
                                                           const float* __restrict__ bias,
                                                           void* __restrict__ outp) {
    __shared__ __align__(16) char lds[40960];  // 2 x (A 4KB + B 16KB)
    const int tid  = threadIdx.x;
    const int wid  = tid >> 6;
    const int lane = tid & 63;
    const int lr   = lane & 15;
    const int g    = lane >> 4;
    const int bm   = blockIdx.x * 64;

    int rowA = bm + lane;
    if (rowA >= N_NODES) rowA = N_NODES - 1;
    const ushort* wBsrc = Wt + ((size_t)(wid * 64 + lane) << 9);

    int aoff[4], boff[4];
#pragma unroll
    for (int f = 0; f < 4; ++f) {
        aoff[f] = g * 1024 + (f * 16 + lr) * 16;
        boff[f] = 4096 + g * 4096 + (wid * 64 + f * 16 + lr) * 16;
    }

    f32x4 acc[4][4];
#pragma unroll
    for (int i = 0; i < 4; ++i)
#pragma unroll
        for (int j = 0; j < 4; ++j) acc[i][j] = (f32x4){0.f, 0.f, 0.f, 0.f};

    STAGE_TILE(0, 0);

#pragma unroll 1
    for (int t = 0; t < 16; ++t) {
        const int cb = (t & 1) * 20480;
        if (t < 15) {
            STAGE_TILE(20480 - cb, t + 1);
            asm volatile("s_waitcnt vmcnt(5)" ::: "memory");
        } else {
            asm volatile("s_waitcnt vmcnt(0)" ::: "memory");
        }
        __builtin_amdgcn_sched_barrier(0);
        __builtin_amdgcn_s_barrier();
        __builtin_amdgcn_sched_barrier(0);
        bf16x8 bfr[4];
#pragma unroll
        for (int fc = 0; fc < 4; ++fc)
            bfr[fc] = *(const bf16x8*)(lds + cb + boff[fc]);
#pragma unroll
        for (int fr = 0; fr < 4; ++fr) {
            bf16x8 af = *(const bf16x8*)(lds + cb + aoff[fr]);
#pragma unroll
            for (int fc = 0; fc < 4; ++fc)
                acc[fr][fc] = __builtin_amdgcn_mfma_f32_16x16x32_bf16(af, bfr[fc],
                                                                      acc[fr][fc], 0, 0, 0);
        }
        __builtin_amdgcn_s_barrier();
    }

    float bv[4];
#pragma unroll
    for (int fc = 0; fc < 4; ++fc) bv[fc] = bias[wid * 64 + fc * 16 + lr];

    if (!OUT_BF16) {
        float* out = (float*)outp;
#pragma unroll
        for (int fr = 0; fr < 4; ++fr)
#pragma unroll
            for (int reg = 0; reg < 4; ++reg) {
                int row = bm + fr * 16 + g * 4 + reg;
                if (row < N_NODES) {
#pragma unroll
                    for (int fc = 0; fc < 4; ++fc)
                        out[(size_t)row * 256 + wid * 64 + fc * 16 + lr] =
                            acc[fr][fc][reg] + bv[fc];
                }
            }
    } else {
        ushort* out = (ushort*)outp;
        float (*L)[260] = (float(*)[260])lds;
#pragma unroll 1
        for (int half = 0; half < 2; ++half) {
            __syncthreads();
#pragma unroll
            for (int fr2 = 0; fr2 < 2; ++fr2) {
                int fr = half * 2 + fr2;
#pragma unroll
                for (int fc = 0; fc < 4; ++fc)
#pragma unroll
                    for (int reg = 0; reg < 4; ++reg) {
                        int r = fr2 * 16 + g * 4 + reg;
                        L[r][wid * 64 + fc * 16 + lr] = fmaxf(acc[fr][fc][reg] + bv[fc], 0.f);
                    }
            }
            __syncthreads();
            int r  = tid >> 3;
            int ch = tid & 7;
            int grow = bm + half * 32 + r;
            if (grow < N_NODES) {
#pragma unroll
                for (int q = 0; q < 4; ++q) {
                    float4 u0 = *(const float4*)&L[r][ch * 32 + q * 8];
                    float4 u1 = *(const float4*)&L[r][ch * 32 + q * 8 + 4];
                    uint2 pk;
                    pk.x = (unsigned)f2b(u0.x) | ((unsigned)f2b(u0.y) << 16);
                    pk.y = (unsigned)f2b(u0.z) | ((unsigned)f2b(u0.w) << 16);
                    uint2 pk2;
                    pk2.x = (unsigned)f2b(u1.x) | ((unsigned)f2b(u1.y) << 16);
                    pk2.y = (unsigned)f2b(u1.z) | ((unsigned)f2b(u1.w) << 16);
                    uint4 w4 = make_uint4(pk.x, pk.y, pk2.x, pk2.y);
                    *(uint4*)&out[(size_t)grow * 256 + ch * 32 + q * 8] = w4;
                }
            }
        }
    }
}

extern "C" void kernel_launch(void* const* d_in, const int* in_sizes, int n_in,
                              void* d_out, int out_size, void* d_ws, size_t ws_size,
                              hipStream_t stream) {
    const float* x     = (const float*)d_in[0];
    const int*   erow  = (const int*)d_in[1];
    const int*   ecol  = (const int*)d_in[2];
    const float* evalv = (const float*)d_in[3];
    const float* W1    = (const float*)d_in[4];
    const float* b1    = (const float*)d_in[5];
    const float* Wout  = (const float*)d_in[6];
    const float* bout  = (const float*)d_in[7];
    float* out = (float*)d_out;

    char* ws = (char*)d_ws;
    size_t off = 0;
    auto alloc = [&](size_t bytes) -> void* {
        void* p = ws + off;
        off += (bytes + 255) & ~(size_t)255;
        return p;
    };
    ushort* xb       = (ushort*)alloc((size_t)N_NODES * D * 2);     // 51.2 MB
    ushort* h1b      = (ushort*)alloc((size_t)N_NODES * D * 2);     // 51.2 MB
    ushort* neighb   = (ushort*)alloc((size_t)N_NODES * D * 2);     // 51.2 MB
    ushort* W1t      = (ushort*)alloc((size_t)512 * 256 * 2);
    ushort* Woutt    = (ushort*)alloc((size_t)512 * 256 * 2);
    int*    bcursor  = (int*)alloc((size_t)NBUCK * sizeof(int));
    int2*   rowrange = (int2*)alloc((size_t)N_NODES * sizeof(int2));      // 0.8 MB
    int2*   staging  = (int2*)alloc((size_t)NBUCK * CAP * sizeof(int2));  // 32.1 MB
    int2*   cedge    = (int2*)alloc((size_t)NBUCK * CAP * sizeof(int2));  // 32.1 MB

    // CSR build
    cursorinit_kernel<<<1, 256, 0, stream>>>(bcursor);
    binpass1_kernel<<<(N_EDGES + EPB - 1) / EPB, 256, 0, stream>>>(erow, ecol, evalv,
                                                                   bcursor, staging);
    binpass2_kernel<<<NBUCK, 256, 0, stream>>>(bcursor, staging, cedge, rowrange);
    // per-row col sort (synchronized-sweep locality for the spmm gathers)
    sortrow_kernel<<<N_NODES / 4, 256, 0, stream>>>(rowrange, cedge);

    // converts
    cvt_kernel<<<(N_NODES * D / 4 + 255) / 256, 256, 0, stream>>>(x, xb, N_NODES * D / 4);
    wtrans_kernel<<<1024, 256, 0, stream>>>(W1, Wout, W1t, Woutt);

    const int gblocks = (N_NODES + 63) / 64;  // 1563
    // layer 1
    spmm_kernel<<<N_NODES / 4, 256, 0, stream>>>(rowrange, cedge, xb, neighb);
    gemm_mfma_kernel<true><<<gblocks, 256, 0, stream>>>(xb, neighb, W1t, b1, h1b);
    // layer 2
    spmm_kernel<<<N_NODES / 4, 256, 0, stream>>>(rowrange, cedge, h1b, neighb);
    gemm_mfma_kernel<false><<<gblocks, 256, 0, stream>>>(h1b, neighb, Woutt, bout, out);
}

// Round 13
// 672.593 us; speedup vs baseline: 1.3147x; 1.3147x over previous
//
#include <hip/hip_runtime.h>
#include <cstddef>
#include <cstdint>

#define N_NODES 100000
#define N_EDGES 3200000
#define D 256
#define BSHIFT 9                                // 512 rows per bucket
#define NBUCK ((N_NODES + (1 << BSHIFT) - 1) >> BSHIFT)  // 196
#define EPB 4096                                // edges per pass-1 block
#define CAP 20480                               // staging slots per bucket

typedef __attribute__((ext_vector_type(8))) short bf16x8;
typedef __attribute__((ext_vector_type(4))) float f32x4;
typedef unsigned int u32;

#define GLOAD16(gsrc, ldst)                                                      \
    __builtin_amdgcn_global_load_lds(                                            \
        (const __attribute__((address_space(1))) void*)(gsrc),                   \
        (__attribute__((address_space(3))) void*)(ldst), 16, 0, 0)

__device__ __forceinline__ ushort f2b(float f) {  // f32 -> bf16 RNE
    unsigned u = __float_as_uint(f);
    return (ushort)((u + 0x7fffu + ((u >> 16) & 1u)) >> 16);
}

// ---------------- bucket cursor init ----------------
__global__ void cursorinit_kernel(int* __restrict__ bucket_cursor) {
    int b = blockIdx.x * 256 + threadIdx.x;
    if (b < NBUCK) bucket_cursor[b] = b * CAP;
}

// ---------------- binned scatter pass 1 ----------------
__global__ __launch_bounds__(256) void binpass1_kernel(const int* __restrict__ erow,
                                                       const int* __restrict__ ecol,
                                                       const float* __restrict__ evalv,
                                                       int* __restrict__ bucket_cursor,
                                                       int2* __restrict__ staging) {
    __shared__ int cnt[NBUCK];
    __shared__ int lstart[NBUCK];
    __shared__ int gbase[NBUCK];
    __shared__ int wtot[4];
    __shared__ int woff[4];
    __shared__ int2 lcv[EPB];            // 32 KB
    __shared__ unsigned char lbb[EPB];   // 4 KB
    const int tid = threadIdx.x;
    const size_t base = (size_t)blockIdx.x * EPB;
    for (int b = tid; b < NBUCK; b += 256) cnt[b] = 0;
    __syncthreads();
    int bb[16];
    int2 pcv[16];
    int loff[16];
#pragma unroll
    for (int i = 0; i < 16; ++i) {
        size_t e = base + (size_t)i * 256 + tid;
        if (e < N_EDGES) {
            int r = erow[e];
            int b = r >> BSHIFT;
            bb[i] = b;
            pcv[i] = make_int2(ecol[e] | ((r & ((1 << BSHIFT) - 1)) << 17),
                               __float_as_int(evalv[e]));
            loff[i] = atomicAdd(&cnt[b], 1);
        } else {
            bb[i] = -1;
        }
    }
    __syncthreads();
    {
        int b = tid;
        int v = (b < NBUCK) ? cnt[b] : 0;
        int lane = tid & 63, wv = tid >> 6;
        int inc = v;
#pragma unroll
        for (int off = 1; off < 64; off <<= 1) {
            int u = __shfl_up(inc, off, 64);
            if (lane >= off) inc += u;
        }
        if (lane == 63) wtot[wv] = inc;
        __syncthreads();
        if (tid == 0) {
            int run = 0;
#pragma unroll
            for (int w = 0; w < 4; ++w) { woff[w] = run; run += wtot[w]; }
        }
        __syncthreads();
        int exc = woff[wv] + inc - v;
        if (b < NBUCK) {
            lstart[b] = exc;
            if (v > 0) gbase[b] = atomicAdd(&bucket_cursor[b], v);
        }
    }
    __syncthreads();
#pragma unroll
    for (int i = 0; i < 16; ++i) {
        if (bb[i] >= 0) {
            int p = lstart[bb[i]] + loff[i];
            lcv[p] = pcv[i];
            lbb[p] = (unsigned char)bb[i];
        }
    }
    __syncthreads();
    const int total = lstart[NBUCK - 1] + cnt[NBUCK - 1];
    for (int p = tid; p < total; p += 256) {
        int b = lbb[p];
        int g = gbase[b] + (p - lstart[b]);
        staging[g] = lcv[p];
    }
}

// ---------------- binned scatter pass 2: count+scan in LDS, emit rowrange --------
__global__ __launch_bounds__(256) void binpass2_kernel(const int* __restrict__ bucket_cursor,
                                                       const int2* __restrict__ staging,
                                                       int2* __restrict__ cedge,
                                                       int2* __restrict__ rowrange) {
    __shared__ int cnt[1 << BSHIFT];
    __shared__ int scur[1 << BSHIFT];
    __shared__ int wtot[4];
    __shared__ int woff[4];
    const int b   = blockIdx.x;
    const int tid = threadIdx.x;
    const int base = b * CAP;
    const int hi   = bucket_cursor[b];
    for (int i = tid; i < (1 << BSHIFT); i += 256) cnt[i] = 0;
    __syncthreads();
    for (int k = base + tid; k < hi; k += 256)
        atomicAdd(&cnt[((u32)staging[k].x) >> 17], 1);
    __syncthreads();
    int v0 = cnt[2 * tid];
    int v1 = cnt[2 * tid + 1];
    int s = v0 + v1;
    int lane = tid & 63, wv = tid >> 6;
    int inc = s;
#pragma unroll
    for (int off = 1; off < 64; off <<= 1) {
        int u = __shfl_up(inc, off, 64);
        if (lane >= off) inc += u;
    }
    if (lane == 63) wtot[wv] = inc;
    __syncthreads();
    if (tid == 0) {
        int run = 0;
#pragma unroll
        for (int w = 0; w < 4; ++w) { woff[w] = run; run += wtot[w]; }
    }
    __syncthreads();
    int exc = woff[wv] + inc - s;
    int g0 = base + exc;
    scur[2 * tid]     = g0;
    scur[2 * tid + 1] = g0 + v0;
    const int r0 = b << BSHIFT;
    int r = r0 + 2 * tid;
    if (r < N_NODES)     rowrange[r]     = make_int2(g0, g0 + v0);
    if (r + 1 < N_NODES) rowrange[r + 1] = make_int2(g0 + v0, g0 + v0 + v1);
    __syncthreads();
    for (int k = base + tid; k < hi; k += 256) {
        int2 e = staging[k];
        int rloc = ((u32)e.x) >> 17;
        int pos = atomicAdd(&scur[rloc], 1);
        cedge[pos] = make_int2(e.x & 0x1FFFF, e.y);
    }
}

// ---------------- f32 -> bf16 elementwise ----------------
__global__ __launch_bounds__(256) void cvt_kernel(const float* __restrict__ in,
                                                  ushort* __restrict__ out, int n4) {
    int i = blockIdx.x * 256 + threadIdx.x;
    if (i < n4) {
        float4 v = ((const float4*)in)[i];
        uint2 p;
        p.x = (unsigned)f2b(v.x) | ((unsigned)f2b(v.y) << 16);
        p.y = (unsigned)f2b(v.z) | ((unsigned)f2b(v.w) << 16);
        ((uint2*)out)[i] = p;
    }
}

// ---------------- W [512][256] f32 -> swizzled Wt bf16 ---------------------------
// Wsz element for (col j, k): j*512 + (((k>>3) ^ (j&63))<<3) + (k&7).
// Linear 1KB-per-col copy into LDS then yields conflict-free (2-way) b128 frag
// reads at lds[j*1024 + ((chunk ^ (j&63))<<4)].
__global__ __launch_bounds__(256) void wtrans_kernel(const float* __restrict__ W1,
                                                     const float* __restrict__ Wout,
                                                     ushort* __restrict__ W1sz,
                                                     ushort* __restrict__ Woutsz) {
    int t = blockIdx.x * 256 + threadIdx.x;       // 0..262143
    const float* W = (t < 131072) ? W1 : Wout;
    ushort* Wsz    = (t < 131072) ? W1sz : Woutsz;
    int u = t & 131071;
    int j = u & 255;
    int k = u >> 8;
    int dst = j * 512 + ((((k >> 3) ^ (j & 63)) << 3) | (k & 7));
    Wsz[dst] = f2b(W[(size_t)k * 256 + j]);
}

// ---------------- CSR SpMM (bf16 features): one wave per node (R6-proven) ---------
__global__ __launch_bounds__(256) void spmm_kernel(const int2* __restrict__ rowrange,
                                                   const int2* __restrict__ cedge,
                                                   const ushort* __restrict__ h,
                                                   ushort* __restrict__ outb) {
    const int node = (blockIdx.x << 2) + (threadIdx.x >> 6);
    const int lane = threadIdx.x & 63;
    const uint2* __restrict__ h2 = (const uint2*)h;
    int2 rr = rowrange[node];
    int k = rr.x;
    const int end = rr.y;
    float a0 = 0.f, a1 = 0.f, a2 = 0.f, a3 = 0.f;
#define EDGE_FMA(e, d)                                              \
    {                                                               \
        float v = __int_as_float((e).y);                            \
        a0 = fmaf(v, __uint_as_float((d).x << 16), a0);             \
        a1 = fmaf(v, __uint_as_float((d).x & 0xffff0000u), a1);     \
        a2 = fmaf(v, __uint_as_float((d).y << 16), a2);             \
        a3 = fmaf(v, __uint_as_float((d).y & 0xffff0000u), a3);     \
    }
    for (; k + 4 <= end; k += 4) {
        int2 e0 = cedge[k];
        int2 e1 = cedge[k + 1];
        int2 e2 = cedge[k + 2];
        int2 e3 = cedge[k + 3];
        uint2 d0 = h2[(size_t)e0.x * 64 + lane];
        uint2 d1 = h2[(size_t)e1.x * 64 + lane];
        uint2 d2 = h2[(size_t)e2.x * 64 + lane];
        uint2 d3 = h2[(size_t)e3.x * 64 + lane];
        EDGE_FMA(e0, d0)
        EDGE_FMA(e1, d1)
        EDGE_FMA(e2, d2)
        EDGE_FMA(e3, d3)
    }
    for (; k < end; ++k) {
        int2 e = cedge[k];
        uint2 d = h2[(size_t)e.x * 64 + lane];
        EDGE_FMA(e, d)
    }
#undef EDGE_FMA
    uint2 p;
    p.x = (unsigned)f2b(a0) | ((unsigned)f2b(a1) << 16);
    p.y = (unsigned)f2b(a2) | ((unsigned)f2b(a3) << 16);
    ((uint2*)outb)[(size_t)node * 64 + lane] = p;
}

// ---------------- MFMA concat-GEMM: B-resident LDS, barrier-free K loop ----------
// Block = 128 rows x 128 cols, 512 threads (8 waves, 2/SIMD). B half (128KB,
// pre-swizzled in global) loaded ONCE; each wave owns 16 rows with a private
// 4-deep A ring (4x1KB) -> K-loop has NO barriers, only per-wave vmcnt(3)
// (3-step prefetch ~450cy covers ~300cy L2 latency). LDS = 128K+32K = 160KB.
template <bool OUT_BF16>
__global__ __launch_bounds__(512, 2) void gemm_mfma_kernel(const ushort* __restrict__ A1,
                                                           const ushort* __restrict__ A2,
                                                           const ushort* __restrict__ Wsz,
                                                           const float* __restrict__ bias,
                                                           void* __restrict__ outp) {
    __shared__ __align__(16) char lds[163840];  // B 0..131071, A rings 131072..163839
    const int tid  = threadIdx.x;
    const int wid  = tid >> 6;                  // 0..7
    const int lane = tid & 63;
    const int lr   = lane & 15;
    const int g    = lane >> 4;
    const int bm   = blockIdx.x * 128;
    const int c0   = blockIdx.y * 128;
    char* const ldsA = lds + 131072 + wid * 4096;

    // A staging source (linear LDS dest = base + lane*16)
    int arow = bm + wid * 16 + (lane >> 2);
    if (arow >= N_NODES) arow = N_NODES - 1;    // clamp; stores guarded
    const int acol = (lane & 3) * 8;

#define STAGE_A(tt)                                                              \
    {                                                                            \
        const ushort* As_ = ((tt) < 8) ? A1 : A2;                                \
        GLOAD16(As_ + (size_t)arow * 256 + ((tt) & 7) * 32 + acol,               \
                ldsA + ((tt) & 3) * 1024);                                       \
    }

    // B frag addressing (per-lane constants)
    int jbyte[8], jx[8];
#pragma unroll
    for (int cf = 0; cf < 8; ++cf) {
        int jl = cf * 16 + lr;
        jbyte[cf] = jl * 1024;
        jx[cf] = jl & 63;
    }

    // prologue: B half (16 x 1KB per wave, linear) + A steps 0..2
#pragma unroll
    for (int q = 0; q < 16; ++q)
        GLOAD16(Wsz + (size_t)c0 * 512 + (wid * 16 + q) * 512 + lane * 8,
                lds + (wid * 16 + q) * 1024);
    STAGE_A(0)
    STAGE_A(1)
    STAGE_A(2)
    asm volatile("s_waitcnt vmcnt(2)" ::: "memory");  // B + A(0) done
    __builtin_amdgcn_sched_barrier(0);
    __builtin_amdgcn_s_barrier();                     // all waves' B slices ready

    f32x4 acc[8];
#pragma unroll
    for (int cf = 0; cf < 8; ++cf) acc[cf] = (f32x4){0.f, 0.f, 0.f, 0.f};

#pragma unroll 1
    for (int t = 0; t < 16; ++t) {
        if (t < 13) {
            STAGE_A(t + 3)
            asm volatile("s_waitcnt vmcnt(3)" ::: "memory");
        } else if (t == 13) {
            asm volatile("s_waitcnt vmcnt(2)" ::: "memory");
        } else if (t == 14) {
            asm volatile("s_waitcnt vmcnt(1)" ::: "memory");
        } else {
            asm volatile("s_waitcnt vmcnt(0)" ::: "memory");
        }
        __builtin_amdgcn_sched_barrier(0);
        const char* Ab = ldsA + (t & 3) * 1024;
        bf16x8 af = *(const bf16x8*)(Ab + lr * 64 + g * 16);
        const int cbase = t * 4 + g;  // k-chunk index 0..63
#pragma unroll
        for (int cf = 0; cf < 8; ++cf) {
            bf16x8 bf_ = *(const bf16x8*)(lds + jbyte[cf] + ((cbase ^ jx[cf]) << 4));
            acc[cf] = __builtin_amdgcn_mfma_f32_16x16x32_bf16(af, bf_, acc[cf], 0, 0, 0);
        }
    }
#undef STAGE_A

    float bv[8];
#pragma unroll
    for (int cf = 0; cf < 8; ++cf) bv[cf] = bias[c0 + cf * 16 + lr];

    if (!OUT_BF16) {
        // direct f32 stores (64B segments per 16-lane group)
        float* out = (float*)outp;
#pragma unroll
        for (int reg = 0; reg < 4; ++reg) {
            int row = bm + wid * 16 + g * 4 + reg;
            if (row < N_NODES) {
#pragma unroll
                for (int cf = 0; cf < 8; ++cf)
                    out[(size_t)row * 256 + c0 + cf * 16 + lr] = acc[cf][reg] + bv[cf];
            }
        }
    } else {
        // relu + bf16 pack via per-wave LDS repack (B region, after barrier)
        __builtin_amdgcn_s_barrier();             // all waves done reading B
        ushort* out = (ushort*)outp;
        float (*L)[132] = (float(*)[132])(lds + wid * 16384);
#pragma unroll
        for (int cf = 0; cf < 8; ++cf)
#pragma unroll
            for (int reg = 0; reg < 4; ++reg)
                L[g * 4 + reg][cf * 16 + lr] = fmaxf(acc[cf][reg] + bv[cf], 0.f);
        asm volatile("s_waitcnt lgkmcnt(0)" ::: "memory");
        __builtin_amdgcn_sched_barrier(0);
        const int r  = lane >> 2;                 // 0..15
        const int cq = lane & 3;
        const int grow = bm + wid * 16 + r;
        if (grow < N_NODES) {
#pragma unroll
            for (int q = 0; q < 4; ++q) {
                int col = q * 32 + cq * 8;
                float4 u0 = *(const float4*)&L[r][col];
                float4 u1 = *(const float4*)&L[r][col + 4];
                uint4 w4;
                w4.x = (unsigned)f2b(u0.x) | ((unsigned)f2b(u0.y) << 16);
                w4.y = (unsigned)f2b(u0.z) | ((unsigned)f2b(u0.w) << 16);
                w4.z = (unsigned)f2b(u1.x) | ((unsigned)f2b(u1.y) << 16);
                w4.w = (unsigned)f2b(u1.z) | ((unsigned)f2b(u1.w) << 16);
                *(uint4*)&out[(size_t)grow * 256 + c0 + col] = w4;
            }
        }
    }
}

extern "C" void kernel_launch(void* const* d_in, const int* in_sizes, int n_in,
                              void* d_out, int out_size, void* d_ws, size_t ws_size,
                              hipStream_t stream) {
    const float* x     = (const float*)d_in[0];
    const int*   erow  = (const int*)d_in[1];
    const int*   ecol  = (const int*)d_in[2];
    const float* evalv = (const float*)d_in[3];
    const float* W1    = (const float*)d_in[4];
    const float* b1    = (const float*)d_in[5];
    const float* Wout  = (const float*)d_in[6];
    const float* bout  = (const float*)d_in[7];
    float* out = (float*)d_out;

    char* ws = (char*)d_ws;
    size_t off = 0;
    auto alloc = [&](size_t bytes) -> void* {
        void* p = ws + off;
        off += (bytes + 255) & ~(size_t)255;
        return p;
    };
    ushort* xb       = (ushort*)alloc((size_t)N_NODES * D * 2);     // 51.2 MB
    ushort* h1b      = (ushort*)alloc((size_t)N_NODES * D * 2);     // 51.2 MB
    ushort* neighb   = (ushort*)alloc((size_t)N_NODES * D * 2);     // 51.2 MB
    ushort* W1sz     = (ushort*)alloc((size_t)512 * 256 * 2);
    ushort* Woutsz   = (ushort*)alloc((size_t)512 * 256 * 2);
    int*    bcursor  = (int*)alloc((size_t)NBUCK * sizeof(int));
    int2*   rowrange = (int2*)alloc((size_t)N_NODES * sizeof(int2));      // 0.8 MB
    int2*   staging  = (int2*)alloc((size_t)NBUCK * CAP * sizeof(int2));  // 32.1 MB
    int2*   cedge    = (int2*)alloc((size_t)NBUCK * CAP * sizeof(int2));  // 32.1 MB

    // CSR build
    cursorinit_kernel<<<1, 256, 0, stream>>>(bcursor);
    binpass1_kernel<<<(N_EDGES + EPB - 1) / EPB, 256, 0, stream>>>(erow, ecol, evalv,
                                                                   bcursor, staging);
    binpass2_kernel<<<NBUCK, 256, 0, stream>>>(bcursor, staging, cedge, rowrange);

    // converts
    cvt_kernel<<<(N_NODES * D / 4 + 255) / 256, 256, 0, stream>>>(x, xb, N_NODES * D / 4);
    wtrans_kernel<<<1024, 256, 0, stream>>>(W1, Wout, W1sz, Woutsz);

    dim3 ggrid((N_NODES + 127) / 128, 2);  // 782 x 2
    // layer 1
    spmm_kernel<<<N_NODES / 4, 256, 0, stream>>>(rowrange, cedge, xb, neighb);
    gemm_mfma_kernel<true><<<ggrid, 512, 0, stream>>>(xb, neighb, W1sz, b1, h1b);
    // layer 2
    spmm_kernel<<<N_NODES / 4, 256, 0, stream>>>(rowrange, cedge, h1b, neighb);
    gemm_mfma_kernel<false><<<ggrid, 512, 0, stream>>>(h1b, neighb, Woutsz, bout, out);
}